// Round 1
// baseline (161.705 us; speedup 1.0000x reference)
//
#include <hip/hip_runtime.h>

#define NBINS 1001
#define HIST_BLOCK 256
#define ELEMS_PER_BLOCK 16384

__device__ __forceinline__ int bin_of(float v) {
    // idx = #{ j in [0,999] : j/999 < v } = clamp(ceil(999*v), 0, 1000)
    double d = ceil((double)v * 999.0);
    int k = (int)d;
    if (k < 0) k = 0;
    if (k > 1000) k = 1000;
    return k;
}

__global__ __launch_bounds__(HIST_BLOCK) void hist_kernel(
    const float* __restrict__ x, const float* __restrict__ y,
    unsigned long long* __restrict__ ghist, int HW, int C)
{
    __shared__ unsigned long long lh[NBINS];
    const int tid = threadIdx.x;
    for (int i = tid; i < NBINS; i += HIST_BLOCK) lh[i] = 0ULL;
    __syncthreads();

    const long long start = (long long)blockIdx.x * ELEMS_PER_BLOCK;
    const int c = (int)((start / HW) % C);   // block lies entirely in one class slab

    const float4* __restrict__ x4 = (const float4*)(x + start);
    const float4* __restrict__ y4 = (const float4*)(y + start);
    const int nvec = ELEMS_PER_BLOCK >> 2;

    for (int i = tid; i < nvec; i += HIST_BLOCK) {
        float4 xv = x4[i];
        float4 yv = y4[i];
        {
            int b = bin_of(xv.x);
            unsigned long long add = 1ULL + ((yv.x > 0.5f) ? (1ULL << 32) : 0ULL);
            atomicAdd(&lh[b], add);
        }
        {
            int b = bin_of(xv.y);
            unsigned long long add = 1ULL + ((yv.y > 0.5f) ? (1ULL << 32) : 0ULL);
            atomicAdd(&lh[b], add);
        }
        {
            int b = bin_of(xv.z);
            unsigned long long add = 1ULL + ((yv.z > 0.5f) ? (1ULL << 32) : 0ULL);
            atomicAdd(&lh[b], add);
        }
        {
            int b = bin_of(xv.w);
            unsigned long long add = 1ULL + ((yv.w > 0.5f) ? (1ULL << 32) : 0ULL);
            atomicAdd(&lh[b], add);
        }
    }
    __syncthreads();

    unsigned long long* gh = ghist + (size_t)c * NBINS;
    for (int i = tid; i < NBINS; i += HIST_BLOCK) {
        unsigned long long v = lh[i];
        if (v) atomicAdd(&gh[i], v);
    }
}

__global__ __launch_bounds__(1024) void f1_kernel(
    const unsigned long long* __restrict__ ghist, float* __restrict__ out, int C)
{
    __shared__ unsigned long long sbuf[1024];
    __shared__ float smax[1024];
    const int tid = threadIdx.x;
    float loss_sum = 0.0f;

    for (int c = 0; c < C; ++c) {
        unsigned long long v = (tid < NBINS) ? ghist[(size_t)c * NBINS + tid] : 0ULL;
        sbuf[tid] = v;
        __syncthreads();
        // Hillis-Steele inclusive scan over 1024 entries (packed: low32=cnt, high32=pos)
        #pragma unroll
        for (int off = 1; off < 1024; off <<= 1) {
            unsigned long long t = (tid >= off) ? sbuf[tid - off] : 0ULL;
            __syncthreads();
            sbuf[tid] += t;
            __syncthreads();
        }
        unsigned long long tot = sbuf[NBINS - 1];  // inclusive total over all bins
        unsigned int total_cnt = (unsigned int)(tot & 0xffffffffULL);   // == N per class
        unsigned int total_y   = (unsigned int)(tot >> 32);

        float f1 = 0.0f;
        if (tid < NBINS - 1) {  // thresholds k = 0..999
            unsigned long long cum = sbuf[tid];
            unsigned int cnt_cum = (unsigned int)(cum & 0xffffffffULL);
            unsigned int y_cum   = (unsigned int)(cum >> 32);
            unsigned int TP = total_y - y_cum;
            unsigned int PP = total_cnt - cnt_cum;
            unsigned int denom = total_y + PP;   // = 2*(TP + 0.5*(FN+FP))
            f1 = (denom == 0u) ? 0.0f : (2.0f * (float)TP) / (float)denom;
        }
        smax[tid] = f1;
        __syncthreads();
        #pragma unroll
        for (int s = 512; s > 0; s >>= 1) {
            if (tid < s) smax[tid] = fmaxf(smax[tid], smax[tid + s]);
            __syncthreads();
        }
        loss_sum += 1.0f - smax[0];
        __syncthreads();   // protect sbuf/smax before next class overwrites
    }

    if (tid == 0) out[0] = loss_sum / (float)C;
}

extern "C" void kernel_launch(void* const* d_in, const int* in_sizes, int n_in,
                              void* d_out, int out_size, void* d_ws, size_t ws_size,
                              hipStream_t stream) {
    const float* x = (const float*)d_in[0];
    const float* y = (const float*)d_in[1];
    float* out = (float*)d_out;

    const int B = 16, C = 4, H = 512, W = 512;
    const int HW = H * W;
    const long long total = (long long)in_sizes[0];   // 16777216

    unsigned long long* ghist = (unsigned long long*)d_ws;

    hipMemsetAsync(d_ws, 0, (size_t)C * NBINS * sizeof(unsigned long long), stream);

    const int nblocks = (int)(total / ELEMS_PER_BLOCK);  // 1024
    hist_kernel<<<nblocks, HIST_BLOCK, 0, stream>>>(x, y, ghist, HW, C);
    f1_kernel<<<1, 1024, 0, stream>>>(ghist, out, C);
    (void)B; (void)n_in; (void)out_size; (void)ws_size;
}

// Round 2
// 151.341 us; speedup vs baseline: 1.0685x; 1.0685x over previous
//
#include <hip/hip_runtime.h>

#define NBINS 1001
#define HIST_BLOCK 256
#define ELEMS_PER_BLOCK 8192

__device__ __forceinline__ int bin_of(float v) {
    // idx = #{ j in [0,999] : j/999 < v } = clamp(ceil(999*v), 0, 1000)
    double d = ceil((double)v * 999.0);
    int k = (int)d;
    if (k < 0) k = 0;
    if (k > 1000) k = 1000;
    return k;
}

// Per-block LDS histogram, packed u32: low 16 bits = count, high 16 = positive count.
// Per-block counts <= 8192 so no field overflow.
__global__ __launch_bounds__(HIST_BLOCK) void hist_kernel(
    const float* __restrict__ x, const float* __restrict__ y,
    unsigned long long* __restrict__ ghist, int HW, int C)
{
    __shared__ unsigned int lh[NBINS];
    const int tid = threadIdx.x;
    for (int i = tid; i < NBINS; i += HIST_BLOCK) lh[i] = 0u;
    __syncthreads();

    const long long start = (long long)blockIdx.x * ELEMS_PER_BLOCK;
    const int c = (int)((start / HW) % C);   // block lies entirely in one class slab

    const float4* __restrict__ x4 = (const float4*)(x + start);
    const float4* __restrict__ y4 = (const float4*)(y + start);

    // 2048 vecs / 256 threads = 8 iters; unroll x2 for 4 independent loads in flight
    #pragma unroll
    for (int ii = 0; ii < 4; ++ii) {
        const int i0 = (ii * 2)     * HIST_BLOCK + tid;
        const int i1 = (ii * 2 + 1) * HIST_BLOCK + tid;
        float4 xa = x4[i0];
        float4 ya = y4[i0];
        float4 xb = x4[i1];
        float4 yb = y4[i1];
        atomicAdd(&lh[bin_of(xa.x)], 1u + ((ya.x > 0.5f) ? 0x10000u : 0u));
        atomicAdd(&lh[bin_of(xa.y)], 1u + ((ya.y > 0.5f) ? 0x10000u : 0u));
        atomicAdd(&lh[bin_of(xa.z)], 1u + ((ya.z > 0.5f) ? 0x10000u : 0u));
        atomicAdd(&lh[bin_of(xa.w)], 1u + ((ya.w > 0.5f) ? 0x10000u : 0u));
        atomicAdd(&lh[bin_of(xb.x)], 1u + ((yb.x > 0.5f) ? 0x10000u : 0u));
        atomicAdd(&lh[bin_of(xb.y)], 1u + ((yb.y > 0.5f) ? 0x10000u : 0u));
        atomicAdd(&lh[bin_of(xb.z)], 1u + ((yb.z > 0.5f) ? 0x10000u : 0u));
        atomicAdd(&lh[bin_of(xb.w)], 1u + ((yb.w > 0.5f) ? 0x10000u : 0u));
    }
    __syncthreads();

    // Flush: unpack u32 -> u64 (low32 = count, high32 = positive count)
    unsigned long long* gh = ghist + (size_t)c * NBINS;
    for (int i = tid; i < NBINS; i += HIST_BLOCK) {
        unsigned int v = lh[i];
        if (v) {
            unsigned long long add = (unsigned long long)(v & 0xffffu)
                                   | ((unsigned long long)(v >> 16) << 32);
            atomicAdd(&gh[i], add);
        }
    }
}

// One block, 1024 threads; thread t owns bin t for all 4 classes.
// Shuffle-based scans: ~3 barriers total (vs ~120 in the Hillis-Steele version).
__global__ __launch_bounds__(1024) void f1_kernel(
    const unsigned long long* __restrict__ ghist, float* __restrict__ out, int C)
{
    __shared__ unsigned long long wtot[4][16];
    __shared__ float wmax[4][16];
    const int tid  = threadIdx.x;
    const int lane = tid & 63;
    const int wave = tid >> 6;

    unsigned long long v[4];
    #pragma unroll
    for (int c = 0; c < 4; ++c)
        v[c] = (tid < NBINS) ? ghist[(size_t)c * NBINS + tid] : 0ULL;

    // intra-wave inclusive scan (u64, packed cnt|ycnt<<32 - fields can't interact)
    #pragma unroll
    for (int off = 1; off < 64; off <<= 1) {
        #pragma unroll
        for (int c = 0; c < 4; ++c) {
            unsigned long long t = __shfl_up(v[c], off, 64);
            if (lane >= off) v[c] += t;
        }
    }
    if (lane == 63) {
        #pragma unroll
        for (int c = 0; c < 4; ++c) wtot[c][wave] = v[c];
    }
    __syncthreads();

    // wave 0: inclusive scan of the 16 wave totals per class.
    // lane = c*16 + w; 16-wide segmented shuffle scan.
    if (wave == 0) {
        const int c = lane >> 4, w = lane & 15;
        unsigned long long t = wtot[c][w];
        #pragma unroll
        for (int off = 1; off < 16; off <<= 1) {
            unsigned long long s = __shfl_up(t, off, 16);
            if (w >= off) t += s;
        }
        wtot[c][w] = t;
    }
    __syncthreads();

    float m[4];
    #pragma unroll
    for (int c = 0; c < 4; ++c) {
        unsigned long long cum = v[c];
        if (wave > 0) cum += wtot[c][wave - 1];
        unsigned long long tot = wtot[c][15];
        unsigned int total_cnt = (unsigned int)(tot & 0xffffffffULL);  // N per class
        unsigned int total_y   = (unsigned int)(tot >> 32);
        float f1 = 0.0f;
        if (tid < NBINS - 1) {  // thresholds k = 0..999
            unsigned int cnt_cum = (unsigned int)(cum & 0xffffffffULL);
            unsigned int y_cum   = (unsigned int)(cum >> 32);
            unsigned int TP = total_y - y_cum;
            unsigned int PP = total_cnt - cnt_cum;
            unsigned int denom = total_y + PP;  // = 2*(TP + 0.5*(FN+FP))
            f1 = (denom == 0u) ? 0.0f : (2.0f * (float)TP) / (float)denom;
        }
        m[c] = f1;
    }

    // wave max-reduce per class
    #pragma unroll
    for (int off = 32; off > 0; off >>= 1) {
        #pragma unroll
        for (int c = 0; c < 4; ++c)
            m[c] = fmaxf(m[c], __shfl_down(m[c], off, 64));
    }
    if (lane == 0) {
        #pragma unroll
        for (int c = 0; c < 4; ++c) wmax[c][wave] = m[c];
    }
    __syncthreads();

    if (tid == 0) {
        float loss = 0.0f;
        #pragma unroll
        for (int c = 0; c < 4; ++c) {
            float mm = wmax[c][0];
            #pragma unroll
            for (int w = 1; w < 16; ++w) mm = fmaxf(mm, wmax[c][w]);
            loss += 1.0f - mm;
        }
        out[0] = loss * 0.25f;
    }
}

extern "C" void kernel_launch(void* const* d_in, const int* in_sizes, int n_in,
                              void* d_out, int out_size, void* d_ws, size_t ws_size,
                              hipStream_t stream) {
    const float* x = (const float*)d_in[0];
    const float* y = (const float*)d_in[1];
    float* out = (float*)d_out;

    const int C = 4, H = 512, W = 512;
    const int HW = H * W;
    const long long total = (long long)in_sizes[0];   // 16777216

    unsigned long long* ghist = (unsigned long long*)d_ws;

    hipMemsetAsync(d_ws, 0, (size_t)C * NBINS * sizeof(unsigned long long), stream);

    const int nblocks = (int)(total / ELEMS_PER_BLOCK);  // 2048
    hist_kernel<<<nblocks, HIST_BLOCK, 0, stream>>>(x, y, ghist, HW, C);
    f1_kernel<<<1, 1024, 0, stream>>>(ghist, out, C);
    (void)n_in; (void)out_size; (void)ws_size;
}

// Round 3
// 151.333 us; speedup vs baseline: 1.0685x; 1.0001x over previous
//
#include <hip/hip_runtime.h>

#define NBINS 1001
#define HIST_BLOCK 1024
#define VEC_PER_THREAD 8                                    // 8 float4 = 32 elems/thread
#define ELEMS_PER_BLOCK (HIST_BLOCK * VEC_PER_THREAD * 4)   // 32768

__device__ __forceinline__ int bin_of(float v) {
    // idx = #{ j in [0,999] : j/999 < v } = clamp(ceil(999*v), 0, 1000)
    // double keeps 999*v exact for fp32 v -> bit-exact vs reference searchsorted
    double d = ceil((double)v * 999.0);
    int k = (int)d;
    if (k < 0) k = 0;
    if (k > 1000) k = 1000;
    return k;
}

// Per-block LDS histogram, packed u32: low16 = count, high16 = positive count.
// Block handles 32768 elems -> fields can't overflow (max 32768 < 65536).
__global__ __launch_bounds__(HIST_BLOCK, 4) void hist_kernel(
    const float* __restrict__ x, const float* __restrict__ y,
    unsigned long long* __restrict__ ghist, int HW, int C)
{
    __shared__ unsigned int lh[NBINS];
    const int tid = threadIdx.x;
    if (tid < NBINS) lh[tid] = 0u;
    __syncthreads();

    const long long start = (long long)blockIdx.x * ELEMS_PER_BLOCK;
    const int c = (int)((start / HW) % C);   // 32768 divides HW=262144: block is class-uniform

    const float4* __restrict__ x4 = (const float4*)(x + start);
    const float4* __restrict__ y4 = (const float4*)(y + start);

    // 2 rounds; each round batch-issues 8 independent 16B loads (4 x + 4 y)
    // BEFORE any atomic consumes them -> ~8KB outstanding per wave (MLP fix).
    #pragma unroll
    for (int r = 0; r < 2; ++r) {
        float4 xv[4], yv[4];
        #pragma unroll
        for (int k = 0; k < 4; ++k) {
            const int idx = (r * 4 + k) * HIST_BLOCK + tid;  // lanes contiguous: coalesced
            xv[k] = x4[idx];
            yv[k] = y4[idx];
        }
        #pragma unroll
        for (int k = 0; k < 4; ++k) {
            atomicAdd(&lh[bin_of(xv[k].x)], 1u + ((yv[k].x > 0.5f) ? 0x10000u : 0u));
            atomicAdd(&lh[bin_of(xv[k].y)], 1u + ((yv[k].y > 0.5f) ? 0x10000u : 0u));
            atomicAdd(&lh[bin_of(xv[k].z)], 1u + ((yv[k].z > 0.5f) ? 0x10000u : 0u));
            atomicAdd(&lh[bin_of(xv[k].w)], 1u + ((yv[k].w > 0.5f) ? 0x10000u : 0u));
        }
    }
    __syncthreads();

    // Flush: unpack u32 -> u64 (low32 = count, high32 = positive count)
    if (tid < NBINS) {
        unsigned int v = lh[tid];
        if (v) {
            unsigned long long add = (unsigned long long)(v & 0xffffu)
                                   | ((unsigned long long)(v >> 16) << 32);
            atomicAdd(&ghist[(size_t)c * NBINS + tid], add);
        }
    }
}

// One block, 1024 threads; thread t owns bin t for all 4 classes.
__global__ __launch_bounds__(1024) void f1_kernel(
    const unsigned long long* __restrict__ ghist, float* __restrict__ out, int C)
{
    __shared__ unsigned long long wtot[4][16];
    __shared__ float wmax[4][16];
    const int tid  = threadIdx.x;
    const int lane = tid & 63;
    const int wave = tid >> 6;

    unsigned long long v[4];
    #pragma unroll
    for (int c = 0; c < 4; ++c)
        v[c] = (tid < NBINS) ? ghist[(size_t)c * NBINS + tid] : 0ULL;

    // intra-wave inclusive scan (u64, packed cnt | ycnt<<32 - fields can't interact)
    #pragma unroll
    for (int off = 1; off < 64; off <<= 1) {
        #pragma unroll
        for (int c = 0; c < 4; ++c) {
            unsigned long long t = __shfl_up(v[c], off, 64);
            if (lane >= off) v[c] += t;
        }
    }
    if (lane == 63) {
        #pragma unroll
        for (int c = 0; c < 4; ++c) wtot[c][wave] = v[c];
    }
    __syncthreads();

    // wave 0: inclusive scan of the 16 wave totals per class (lane = c*16 + w)
    if (wave == 0) {
        const int c = lane >> 4, w = lane & 15;
        unsigned long long t = wtot[c][w];
        #pragma unroll
        for (int off = 1; off < 16; off <<= 1) {
            unsigned long long s = __shfl_up(t, off, 16);
            if (w >= off) t += s;
        }
        wtot[c][w] = t;
    }
    __syncthreads();

    float m[4];
    #pragma unroll
    for (int c = 0; c < 4; ++c) {
        unsigned long long cum = v[c];
        if (wave > 0) cum += wtot[c][wave - 1];
        unsigned long long tot = wtot[c][15];
        unsigned int total_cnt = (unsigned int)(tot & 0xffffffffULL);  // N per class
        unsigned int total_y   = (unsigned int)(tot >> 32);
        float f1 = 0.0f;
        if (tid < NBINS - 1) {  // thresholds k = 0..999
            unsigned int cnt_cum = (unsigned int)(cum & 0xffffffffULL);
            unsigned int y_cum   = (unsigned int)(cum >> 32);
            unsigned int TP = total_y - y_cum;
            unsigned int PP = total_cnt - cnt_cum;
            unsigned int denom = total_y + PP;  // = 2*(TP + 0.5*(FN+FP))
            f1 = (denom == 0u) ? 0.0f : (2.0f * (float)TP) / (float)denom;
        }
        m[c] = f1;
    }

    // wave max-reduce per class
    #pragma unroll
    for (int off = 32; off > 0; off >>= 1) {
        #pragma unroll
        for (int c = 0; c < 4; ++c)
            m[c] = fmaxf(m[c], __shfl_down(m[c], off, 64));
    }
    if (lane == 0) {
        #pragma unroll
        for (int c = 0; c < 4; ++c) wmax[c][wave] = m[c];
    }
    __syncthreads();

    if (tid == 0) {
        float loss = 0.0f;
        #pragma unroll
        for (int c = 0; c < 4; ++c) {
            float mm = wmax[c][0];
            #pragma unroll
            for (int w = 1; w < 16; ++w) mm = fmaxf(mm, wmax[c][w]);
            loss += 1.0f - mm;
        }
        out[0] = loss * 0.25f;
    }
}

extern "C" void kernel_launch(void* const* d_in, const int* in_sizes, int n_in,
                              void* d_out, int out_size, void* d_ws, size_t ws_size,
                              hipStream_t stream) {
    const float* x = (const float*)d_in[0];
    const float* y = (const float*)d_in[1];
    float* out = (float*)d_out;

    const int C = 4, H = 512, W = 512;
    const int HW = H * W;
    const long long total = (long long)in_sizes[0];   // 16777216

    unsigned long long* ghist = (unsigned long long*)d_ws;

    hipMemsetAsync(d_ws, 0, (size_t)C * NBINS * sizeof(unsigned long long), stream);

    const int nblocks = (int)(total / ELEMS_PER_BLOCK);  // 512
    hist_kernel<<<nblocks, HIST_BLOCK, 0, stream>>>(x, y, ghist, HW, C);
    f1_kernel<<<1, 1024, 0, stream>>>(ghist, out, C);
    (void)n_in; (void)out_size; (void)ws_size;
}